// Round 1
// 210.538 us; speedup vs baseline: 1.1438x; 1.1438x over previous
//
#include <hip/hip_runtime.h>
#include <hip/hip_fp16.h>
#include <math.h>

#define N_NODES 100000
#define N_EDGES 1600000
#define EP (N_EDGES + N_NODES)   // edges incl self-loops
#define HID 64
#define NCHUNK 128                               // scatter chunks
#define CE (N_EDGES / NCHUNK)                    // 12500 edges per chunk (exact)
#define NBUCK 391                                // buckets of 256 node-keys
#define CAP 5120                                 // fixed ebuf window per bucket (mean 4096, 16 sigma)
#define NTILE (N_NODES / 16)                     // 6250 tiles = blocks (exact)
#define STASH 8192                               // per-bucket stash (u32)
#define OBSTRIDE 4096                            // u64 overflow slots per bucket
#define NPN 4                                    // nodes per wave (gather), even

typedef _Float16 half8_t __attribute__((ext_vector_type(8)));
typedef _Float16 half4_t __attribute__((ext_vector_type(4)));
typedef float f32x4_t __attribute__((ext_vector_type(4)));
typedef unsigned long long u64;

// ================= bucketed CSR build v6 (fixed-capacity, no hist/scan stage) =================

// init: gcur[b] = window start; zero csr pad

__global__ void init_kernel(int* __restrict__ gcur, int* __restrict__ csr) {
    int t = threadIdx.x;
    for (int b = t; b < NBUCK; b += 512) gcur[b] = b * CAP;
    if (t < 64) csr[EP + t] = 0;
}

// scatter: per-block LDS hist -> one global reserve per (block,bucket) -> packed scatter

__global__ __launch_bounds__(1024)
void scatter_kernel(const int* __restrict__ src, const int* __restrict__ dst,
                    int* __restrict__ gcur, unsigned* __restrict__ ebuf) {
    __shared__ int hist[NBUCK];
    __shared__ int cur[NBUCK];
    const int tid = threadIdx.x, c = blockIdx.x;
    for (int b = tid; b < NBUCK; b += 1024) hist[b] = 0;
    __syncthreads();
    const int4* d4p = (const int4*)(dst + c * CE);
    const int4* s4p = (const int4*)(src + c * CE);
    for (int t = tid; t < CE / 4; t += 1024) {
        int4 d = d4p[t];
        atomicAdd(&hist[d.x >> 8], 1);
        atomicAdd(&hist[d.y >> 8], 1);
        atomicAdd(&hist[d.z >> 8], 1);
        atomicAdd(&hist[d.w >> 8], 1);
    }
    __syncthreads();
    for (int b = tid; b < NBUCK; b += 1024)
        cur[b] = hist[b] ? atomicAdd(&gcur[b], hist[b]) : 0;
    __syncthreads();
    for (int t = tid; t < CE / 4; t += 1024) {
        int4 s = s4p[t];
        int4 d = d4p[t];
        int p0 = atomicAdd(&cur[d.x >> 8], 1);
        ebuf[p0] = ((unsigned)(d.x & 255) << 17) | (unsigned)s.x;   // src < 2^17
        int p1 = atomicAdd(&cur[d.y >> 8], 1);
        ebuf[p1] = ((unsigned)(d.y & 255) << 17) | (unsigned)s.y;
        int p2 = atomicAdd(&cur[d.z >> 8], 1);
        ebuf[p2] = ((unsigned)(d.z & 255) << 17) | (unsigned)s.z;
        int p3 = atomicAdd(&cur[d.w >> 8], 1);
        ebuf[p3] = ((unsigned)(d.w & 255) << 17) | (unsigned)s.w;
    }
}

// bscan: exclusive scan of (bucket edge count + 256 self-loops) -> bucket rowptr base

__global__ void bscan_kernel(const int* __restrict__ gcur, int* __restrict__ bR0) {
    __shared__ int tmp[512];
    int t = threadIdx.x;
    int v = (t < NBUCK) ? (gcur[t] - t * CAP + 256) : 0;
    tmp[t] = v;
    __syncthreads();
    for (int off = 1; off < 512; off <<= 1) {
        int y = (t >= off) ? tmp[t - off] : 0;
        __syncthreads();
        tmp[t] += y;
        __syncthreads();
    }
    if (t < NBUCK) bR0[t] = tmp[t] - v;   // exclusive prefix
}

// rankfill: per-bucket rank; cnt scan -> rowptr/dinv/self-loop; csr fill
// also emits xd[n] = float4(dinv[n] * x[n], pad) for the 3-dim layer-1 gather

__global__ __launch_bounds__(256)
void rankfill_kernel(const unsigned* __restrict__ ebuf, const int* __restrict__ gcur,
                     const int* __restrict__ bR0, u64* __restrict__ obuf,
                     int* __restrict__ rowptr, int* __restrict__ csr,
                     float* __restrict__ dinv,
                     const float* __restrict__ x, float4* __restrict__ xd) {
    __shared__ int cnt[256];
    __shared__ int rpl[256];
    __shared__ int wsum[4];
    __shared__ int ocnt;
    __shared__ unsigned stash[STASH];
    const int tid = threadIdx.x, b = blockIdx.x;
    cnt[tid] = 0;
    if (tid == 0) ocnt = 0;
    __syncthreads();
    const int E0 = b * CAP;
    const int RL = gcur[b] - E0;          // bucket edge count
    const int R0 = bR0[b];                // global rowptr base for this bucket
    for (int off = tid; off < RL; off += 256) {
        unsigned v = ebuf[E0 + off];
        int key = (v >> 17) & 0xFF;
        int r = atomicAdd(&cnt[key], 1);
        if (off < STASH && r < 128) {
            stash[off] = ((unsigned)r << 25) | v;
        } else {
            if (off < STASH) stash[off] = 0xFFFFFFFFu;
            int oi = (off >= STASH) ? (off - STASH) : (2048 + atomicAdd(&ocnt, 1));
            obuf[(size_t)b * OBSTRIDE + oi] =
                ((u64)r << 40) | ((u64)key << 32) | (u64)(v & 0x1FFFFu);
        }
    }
    __syncthreads();
    const int lane = tid & 63, w = tid >> 6;
    int xcnt = cnt[tid];
    int inc = xcnt;
#pragma unroll
    for (int off = 1; off < 64; off <<= 1) {
        int y = __shfl_up(inc, off, 64);
        if (lane >= off) inc += y;
    }
    if (lane == 63) wsum[w] = inc;
    __syncthreads();
    int base = 0;
    for (int k = 0; k < 4; ++k) if (k < w) base += wsum[k];
    int pre = base + inc - xcnt;
    const int n = b * 256 + tid;
    const int rpn = R0 + tid + pre;       // bucket base + in-bucket self-loops + edge prefix
    rpl[tid] = rpn;
    if (n < N_NODES) {
        rowptr[n] = rpn;
        float di = rsqrtf((float)(xcnt + 1));
        dinv[n] = di;
        csr[rpn + xcnt] = n;              // self-loop at end of node's list
        xd[n] = make_float4(x[n * 3 + 0] * di, x[n * 3 + 1] * di, x[n * 3 + 2] * di, 0.f);
    }
    if (b == NBUCK - 1 && tid == 0) rowptr[N_NODES] = EP;
    __syncthreads();
    const int lim = (RL < STASH) ? RL : STASH;
    for (int off = tid; off < lim; off += 256) {
        unsigned v = stash[off];
        if (v == 0xFFFFFFFFu) continue;
        csr[rpl[(v >> 17) & 0xFF] + (v >> 25)] = (int)(v & 0x1FFFFu);
    }
    for (int j = tid; j < RL - STASH; j += 256) {       // ≈ never
        u64 pk = obuf[(size_t)b * OBSTRIDE + j];
        csr[rpl[(pk >> 32) & 0xFF] + (int)(pk >> 40)] = (int)(pk & 0x1FFFFu);
    }
    for (int j = tid; j < ocnt; j += 256) {             // ≈ never
        u64 pk = obuf[(size_t)b * OBSTRIDE + 2048 + j];
        csr[rpl[(pk >> 32) & 0xFF] + (int)(pk >> 40)] = (int)(pk & 0x1FFFFu);
    }
}

// ================= fused layer (R17-proven): block = 16-node tile =================

__device__ __forceinline__ void addp(float4& a, uint2 u, bool pred) {
    __half2 h0 = *(__half2*)&u.x, h1 = *(__half2*)&u.y;
    float2 x = __half22float2(h0), y = __half22float2(h1);
    if (pred) { a.x += x.x; a.y += x.y; a.z += y.x; a.w += y.y; }
}

__device__ __forceinline__ void bfly_store_lds(float4 acc, const float4 b4, float di,
                                               int g, int p, int l, _Float16* __restrict__ tl) {
    acc.x += __shfl_xor(acc.x, 16, 64);
    acc.y += __shfl_xor(acc.y, 16, 64);
    acc.z += __shfl_xor(acc.z, 16, 64);
    acc.w += __shfl_xor(acc.w, 16, 64);
    acc.x += __shfl_xor(acc.x, 32, 64);
    acc.y += __shfl_xor(acc.y, 32, 64);
    acc.z += __shfl_xor(acc.z, 32, 64);
    acc.w += __shfl_xor(acc.w, 32, 64);
    if (g == 0) {
        half4_t hv;
        hv[0] = (_Float16)fmaxf(fmaf(di, acc.x, b4.x), 0.f);
        hv[1] = (_Float16)fmaxf(fmaf(di, acc.y, b4.y), 0.f);
        hv[2] = (_Float16)fmaxf(fmaf(di, acc.z, b4.z), 0.f);
        hv[3] = (_Float16)fmaxf(fmaf(di, acc.w, b4.w), 0.f);
        *(half4_t*)(tl + l * 72 + p * 4) = hv;
    }
}

__device__ __forceinline__ void gather_phase(const __half* __restrict__ gf,
                                             const int* __restrict__ rowptr,
                                             const int* __restrict__ csr,
                                             const float* __restrict__ dinv,
                                             const float* __restrict__ bias,
                                             int n0, int lane, int wid,
                                             _Float16* __restrict__ tl) {
    const int g = lane >> 4, p = lane & 15;
    const int nw = n0 + wid * NPN;
    int rp = rowptr[nw + min(lane, NPN)];
    const uint2* gf2 = (const uint2*)gf;
    const float4 b4 = ((const float4*)bias)[p];
    int begv[NPN], cntv[NPN], idxv[NPN];
    int end_prev = __shfl(rp, 0, 64);
#pragma unroll
    for (int i = 0; i < NPN; ++i) {
        int end = __shfl(rp, i + 1, 64);
        begv[i] = end_prev;
        cntv[i] = end - end_prev;
        end_prev = end;
        // predicated: masked lanes skip -> fewer 64B segments fetched
        idxv[i] = (lane < cntv[i]) ? csr[begv[i] + lane] : 0;
    }
#pragma unroll
    for (int ii = 0; ii < NPN; ii += 2) {
        const int la = wid * NPN + ii, lb = la + 1;
        const int ca = cntv[ii], cb = cntv[ii + 1];
        const int ba = begv[ii], bb = begv[ii + 1];
        const int iva = idxv[ii], ivb = idxv[ii + 1];
        int sa0 = __shfl(iva, g, 64),      sb0 = __shfl(ivb, g, 64);
        int sa1 = __shfl(iva, g + 4, 64),  sb1 = __shfl(ivb, g + 4, 64);
        int sa2 = __shfl(iva, g + 8, 64),  sb2 = __shfl(ivb, g + 8, 64);
        int sa3 = __shfl(iva, g + 12, 64), sb3 = __shfl(ivb, g + 12, 64);
        uint2 ua0 = gf2[(size_t)sa0 * 16 + p], ub0 = gf2[(size_t)sb0 * 16 + p];
        uint2 ua1 = gf2[(size_t)sa1 * 16 + p], ub1 = gf2[(size_t)sb1 * 16 + p];
        uint2 ua2 = gf2[(size_t)sa2 * 16 + p], ub2 = gf2[(size_t)sb2 * 16 + p];
        uint2 ua3 = gf2[(size_t)sa3 * 16 + p], ub3 = gf2[(size_t)sb3 * 16 + p];
        float4 accA = make_float4(0.f, 0.f, 0.f, 0.f);
        float4 accB = make_float4(0.f, 0.f, 0.f, 0.f);
        addp(accA, ua0, g + 0 < ca);  addp(accB, ub0, g + 0 < cb);
        addp(accA, ua1, g + 4 < ca);  addp(accB, ub1, g + 4 < cb);
        addp(accA, ua2, g + 8 < ca);  addp(accB, ub2, g + 8 < cb);
        addp(accA, ua3, g + 12 < ca); addp(accB, ub3, g + 12 < cb);
        if (ca > 16) {
#pragma unroll
            for (int k = 4; k < 8; ++k) {
                int e = g + 4 * k;
                int s = __shfl(iva, e, 64);
                addp(accA, gf2[(size_t)s * 16 + p], e < ca);
            }
            if (ca > 32) {
                for (int e = 32 + g; e < ca; e += 4) {
                    int s = (e < 64) ? __shfl(iva, e, 64) : csr[ba + e];
                    addp(accA, gf2[(size_t)s * 16 + p], true);
                }
            }
        }
        if (cb > 16) {
#pragma unroll
            for (int k = 4; k < 8; ++k) {
                int e = g + 4 * k;
                int s = __shfl(ivb, e, 64);
                addp(accB, gf2[(size_t)s * 16 + p], e < cb);
            }
            if (cb > 32) {
                for (int e = 32 + g; e < cb; e += 4) {
                    int s = (e < 64) ? __shfl(ivb, e, 64) : csr[bb + e];
                    addp(accB, gf2[(size_t)s * 16 + p], true);
                }
            }
        }
        bfly_store_lds(accA, b4, dinv[n0 + la], g, p, la, tl);
        bfly_store_lds(accB, b4, dinv[n0 + lb], g, p, lb, tl);
    }
}

// ================= fused layer 1: 3-dim fp32 gather (linearity: agg before @W1) =================
// out[d] = dinv[d] * (Σ_{s∈N(d)∪{d}} dinv[s]*x[s]) @ W1 + b1 ; relu ; then @W2 MFMA tail.
// xd (1.6 MB float4) is L2-resident on every XCD -> 16 B/edge instead of 128 B/edge.

__global__ __launch_bounds__(256, 8)
void fused_layer1_kernel(const float4* __restrict__ xd, const int* __restrict__ rowptr,
                         const int* __restrict__ csr, const float* __restrict__ dinv,
                         const float* __restrict__ b1, const float* __restrict__ W1,
                         const float* __restrict__ W2, __half* __restrict__ gf_out) {
    __shared__ __align__(16) _Float16 tile[16 * 72];
    __shared__ __align__(16) _Float16 tile2[16 * 72];
    const int tid = threadIdx.x;
    const int lane = tid & 63, wid = tid >> 6;
    const int n0 = blockIdx.x * 16;

    // ---- 3-dim gather: node j = lane>>4 within wave, 16 lanes per node ----
    const int j = lane >> 4, p = lane & 15;
    const int l = wid * 4 + j;            // tile-local node 0..15
    const int node = n0 + l;
    const int beg = rowptr[node], end = rowptr[node + 1];
    float a0 = 0.f, a1 = 0.f, a2 = 0.f;
    for (int e = beg + p; e < end; e += 16) {
        float4 v = xd[csr[e]];
        a0 += v.x; a1 += v.y; a2 += v.z;
    }
#pragma unroll
    for (int off = 1; off < 16; off <<= 1) {
        a0 += __shfl_xor(a0, off, 64);
        a1 += __shfl_xor(a1, off, 64);
        a2 += __shfl_xor(a2, off, 64);
    }
    const float dd = dinv[node];
    const float4 w0 = ((const float4*)W1)[p];
    const float4 w1 = ((const float4*)(W1 + HID))[p];
    const float4 w2 = ((const float4*)(W1 + 2 * HID))[p];
    const float4 bb = ((const float4*)b1)[p];
    half4_t hv;
    hv[0] = (_Float16)fmaxf(fmaf(dd, a0 * w0.x + a1 * w1.x + a2 * w2.x, bb.x), 0.f);
    hv[1] = (_Float16)fmaxf(fmaf(dd, a0 * w0.y + a1 * w1.y + a2 * w2.y, bb.y), 0.f);
    hv[2] = (_Float16)fmaxf(fmaf(dd, a0 * w0.z + a1 * w1.z + a2 * w2.z, bb.z), 0.f);
    hv[3] = (_Float16)fmaxf(fmaf(dd, a0 * w0.w + a1 * w1.w + a2 * w2.w, bb.w), 0.f);
    *(half4_t*)(tile + l * 72 + p * 4) = hv;
    __syncthreads();

    // ---- MFMA tail: gf_out = dinv ⊙ (h1 @ W2), identical to fused_layer ----
    const int kg = lane >> 4, n = lane & 15;
    half8_t B0, B1;
#pragma unroll
    for (int jj = 0; jj < 8; ++jj) {
        B0[jj] = (_Float16)W2[(kg * 8 + jj) * HID + wid * 16 + n];
        B1[jj] = (_Float16)W2[(32 + kg * 8 + jj) * HID + wid * 16 + n];
    }
    half8_t A0 = *(const half8_t*)(tile + n * 72 + kg * 8);
    half8_t A1 = *(const half8_t*)(tile + n * 72 + 32 + kg * 8);
    f32x4_t c = {0.f, 0.f, 0.f, 0.f};
    c = __builtin_amdgcn_mfma_f32_16x16x32_f16(A0, B0, c, 0, 0, 0);
    c = __builtin_amdgcn_mfma_f32_16x16x32_f16(A1, B1, c, 0, 0, 0);

    const int q = lane >> 4;
#pragma unroll
    for (int r = 0; r < 4; ++r)
        tile2[(q * 4 + r) * 72 + wid * 16 + n] = (_Float16)(c[r] * dinv[n0 + q * 4 + r]);
    __syncthreads();
    const int row = tid >> 4, seg = tid & 15;
    uint2 v = *(const uint2*)(tile2 + row * 72 + seg * 4);
    *(uint2*)((__half*)gf_out + (size_t)(n0 + row) * HID + seg * 4) = v;
}

__global__ __launch_bounds__(256, 8)
void fused_layer_kernel(const __half* __restrict__ gf_in, const int* __restrict__ rowptr,
                        const int* __restrict__ csr, const float* __restrict__ dinv,
                        const float* __restrict__ bias, const float* __restrict__ W,
                        __half* __restrict__ gf_out) {
    __shared__ __align__(16) _Float16 tile[16 * 72];
    __shared__ __align__(16) _Float16 tile2[16 * 72];
    const int tid = threadIdx.x;
    const int lane = tid & 63, wid = tid >> 6;
    const int n0 = blockIdx.x * 16;

    gather_phase(gf_in, rowptr, csr, dinv, bias, n0, lane, wid, tile);
    __syncthreads();

    const int kg = lane >> 4, n = lane & 15;
    half8_t B0, B1;
#pragma unroll
    for (int j = 0; j < 8; ++j) {
        B0[j] = (_Float16)W[(kg * 8 + j) * HID + wid * 16 + n];
        B1[j] = (_Float16)W[(32 + kg * 8 + j) * HID + wid * 16 + n];
    }
    half8_t A0 = *(const half8_t*)(tile + n * 72 + kg * 8);
    half8_t A1 = *(const half8_t*)(tile + n * 72 + 32 + kg * 8);
    f32x4_t c = {0.f, 0.f, 0.f, 0.f};
    c = __builtin_amdgcn_mfma_f32_16x16x32_f16(A0, B0, c, 0, 0, 0);
    c = __builtin_amdgcn_mfma_f32_16x16x32_f16(A1, B1, c, 0, 0, 0);

    const int q = lane >> 4;
#pragma unroll
    for (int r = 0; r < 4; ++r)
        tile2[(q * 4 + r) * 72 + wid * 16 + n] = (_Float16)(c[r] * dinv[n0 + q * 4 + r]);
    __syncthreads();
    const int row = tid >> 4, seg = tid & 15;
    uint2 v = *(const uint2*)(tile2 + row * 72 + seg * 4);
    *(uint2*)((__half*)gf_out + (size_t)(n0 + row) * HID + seg * 4) = v;
}

// ================= fused final: gather -> hv LDS -> MFMA(Wm1) + head + sigmoid =================

__global__ __launch_bounds__(256, 8)
void fused_final_kernel(const __half* __restrict__ gf_in, const int* __restrict__ rowptr,
                        const int* __restrict__ csr, const float* __restrict__ dinv,
                        const float* __restrict__ b3, const float* __restrict__ Wm1,
                        const float* __restrict__ bm1, const float* __restrict__ Wm2,
                        const float* __restrict__ bm2, float* __restrict__ out) {
    __shared__ __align__(16) _Float16 tile[16 * 72];
    __shared__ float redbuf[4][16];
    const int tid = threadIdx.x;
    const int lane = tid & 63, wid = tid >> 6;
    const int n0 = blockIdx.x * 16;

    gather_phase(gf_in, rowptr, csr, dinv, b3, n0, lane, wid, tile);
    __syncthreads();

    const int kg = lane >> 4, n = lane & 15;
    half8_t B0, B1;
#pragma unroll
    for (int j = 0; j < 8; ++j) {
        B0[j] = (_Float16)Wm1[(kg * 8 + j) * HID + wid * 16 + n];
        B1[j] = (_Float16)Wm1[(32 + kg * 8 + j) * HID + wid * 16 + n];
    }
    half8_t A0 = *(const half8_t*)(tile + n * 72 + kg * 8);
    half8_t A1 = *(const half8_t*)(tile + n * 72 + 32 + kg * 8);
    f32x4_t c = {0.f, 0.f, 0.f, 0.f};
    c = __builtin_amdgcn_mfma_f32_16x16x32_f16(A0, B0, c, 0, 0, 0);
    c = __builtin_amdgcn_mfma_f32_16x16x32_f16(A1, B1, c, 0, 0, 0);

    const float bm1c = bm1[wid * 16 + n];
    const float wm2c = Wm2[wid * 16 + n];
    float part[4];
#pragma unroll
    for (int r = 0; r < 4; ++r) part[r] = fmaxf(c[r] + bm1c, 0.0f) * wm2c;
#pragma unroll
    for (int off = 1; off < 16; off <<= 1)
#pragma unroll
        for (int r = 0; r < 4; ++r) part[r] += __shfl_xor(part[r], off, 64);
    const int q = lane >> 4;
    if (n == 0) {
#pragma unroll
        for (int r = 0; r < 4; ++r) redbuf[wid][q * 4 + r] = part[r];
    }
    __syncthreads();
    if (tid < 16) {
        float s = redbuf[0][tid] + redbuf[1][tid] + redbuf[2][tid] + redbuf[3][tid];
        out[n0 + tid] = 1.0f / (1.0f + expf(-(s + bm2[0])));
    }
}

// ---------------- launch ----------------

extern "C" void kernel_launch(void* const* d_in, const int* in_sizes, int n_in,
                              void* d_out, int out_size, void* d_ws, size_t ws_size,
                              hipStream_t stream) {
    const float* x   = (const float*)d_in[0];
    const int*   ei  = (const int*)d_in[1];
    const float* W1  = (const float*)d_in[2];
    const float* b1  = (const float*)d_in[3];
    const float* W2  = (const float*)d_in[4];
    const float* b2  = (const float*)d_in[5];
    const float* W3  = (const float*)d_in[6];
    const float* b3  = (const float*)d_in[7];
    const float* Wm1 = (const float*)d_in[8];
    const float* bm1 = (const float*)d_in[9];
    const float* Wm2 = (const float*)d_in[10];
    const float* bm2 = (const float*)d_in[11];
    float* out = (float*)d_out;

    const int* src = ei;
    const int* dst = ei + N_EDGES;

    char* ws = (char*)d_ws;
    size_t off = 0;
    auto alloc = [&](size_t bytes) { size_t o = off; off = (off + bytes + 255) & ~(size_t)255; return (void*)(ws + o); };
    int*      rowptr = (int*)alloc(4ll * (N_NODES + 1));
    int*      gcur   = (int*)alloc(4ll * NBUCK);
    int*      bR0    = (int*)alloc(4ll * NBUCK);
    int*      csr    = (int*)alloc(4ll * (EP + 64));       // +64 pad (zeros)
    float*    dinv   = (float*)alloc(4ll * N_NODES);
    float4*   xd     = (float4*)alloc(16ll * N_NODES);     // dinv*x packed, 1.6 MB (L2-resident)
    __half*   gfA    = (__half*)alloc(2ll * N_NODES * HID);
    __half*   gfB    = (__half*)alloc(2ll * N_NODES * HID);
    unsigned* ebuf   = (unsigned*)alloc(4ll * (size_t)NBUCK * CAP);
    u64*      obuf   = (u64*)alloc(8ll * (size_t)NBUCK * OBSTRIDE);
    (void)ws_size;

    // --- CSR build v6: 4 dispatches, fixed-capacity buckets ---
    init_kernel<<<1, 512, 0, stream>>>(gcur, csr);
    scatter_kernel<<<NCHUNK, 1024, 0, stream>>>(src, dst, gcur, ebuf);
    bscan_kernel<<<1, 512, 0, stream>>>(gcur, bR0);
    rankfill_kernel<<<NBUCK, 256, 0, stream>>>(ebuf, gcur, bR0, obuf, rowptr, csr, dinv, x, xd);

    // --- layers: layer1 folded into fused_layer1 via linearity (3-dim fp32 gather) ---
    fused_layer1_kernel<<<NTILE, 256, 0, stream>>>(xd, rowptr, csr, dinv, b1, W1, W2, gfB);
    fused_layer_kernel<<<NTILE, 256, 0, stream>>>(gfB, rowptr, csr, dinv, b2, W3, gfA);
    fused_final_kernel<<<NTILE, 256, 0, stream>>>(gfA, rowptr, csr, dinv, b3, Wm1, bm1, Wm2, bm2, out);
}

// Round 2
// 207.551 us; speedup vs baseline: 1.1603x; 1.0144x over previous
//
#include <hip/hip_runtime.h>
#include <hip/hip_fp16.h>
#include <math.h>

#define N_NODES 100000
#define N_EDGES 1600000
#define EP (N_EDGES + N_NODES)   // edges incl self-loops
#define HID 64
#define NCHUNK 250                               // scatter chunks (>= 1 block per CU)
#define CE (N_EDGES / NCHUNK)                    // 6400 edges per chunk (exact, /4 ok)
#define NBUCK 782                                // buckets of 128 node-keys (ceil(1e5/128))
#define CAP 2816                                 // fixed ebuf window per bucket (mean 2048, +17 sigma)
#define NTILE (N_NODES / 16)                     // 6250 tiles = blocks (exact)
#define STASH CAP                                // stash covers the whole bucket window
#define OBSTRIDE 512                             // u64 overflow slots per bucket (rank>=128 only)
#define NPN 4                                    // nodes per wave (gather), even

typedef _Float16 half8_t __attribute__((ext_vector_type(8)));
typedef _Float16 half4_t __attribute__((ext_vector_type(4)));
typedef float f32x4_t __attribute__((ext_vector_type(4)));
typedef unsigned long long u64;

// ================= bucketed CSR build v7 (128-node buckets, occupancy-fixed) =================

// init: gcur[b] = window start; zero csr pad

__global__ void init_kernel(int* __restrict__ gcur, int* __restrict__ csr) {
    int t = threadIdx.x;
    for (int b = t; b < NBUCK; b += 512) gcur[b] = b * CAP;
    if (t < 64) csr[EP + t] = 0;
}

// scatter: per-block LDS hist -> one global reserve per (block,bucket) -> packed scatter

__global__ __launch_bounds__(1024)
void scatter_kernel(const int* __restrict__ src, const int* __restrict__ dst,
                    int* __restrict__ gcur, unsigned* __restrict__ ebuf) {
    __shared__ int hist[NBUCK];
    __shared__ int cur[NBUCK];
    const int tid = threadIdx.x, c = blockIdx.x;
    for (int b = tid; b < NBUCK; b += 1024) hist[b] = 0;
    __syncthreads();
    const int4* d4p = (const int4*)(dst + c * CE);
    const int4* s4p = (const int4*)(src + c * CE);
    for (int t = tid; t < CE / 4; t += 1024) {
        int4 d = d4p[t];
        atomicAdd(&hist[d.x >> 7], 1);
        atomicAdd(&hist[d.y >> 7], 1);
        atomicAdd(&hist[d.z >> 7], 1);
        atomicAdd(&hist[d.w >> 7], 1);
    }
    __syncthreads();
    for (int b = tid; b < NBUCK; b += 1024)
        cur[b] = hist[b] ? atomicAdd(&gcur[b], hist[b]) : 0;
    __syncthreads();
    for (int t = tid; t < CE / 4; t += 1024) {
        int4 s = s4p[t];
        int4 d = d4p[t];
        int p0 = atomicAdd(&cur[d.x >> 7], 1);
        ebuf[p0] = ((unsigned)(d.x & 127) << 17) | (unsigned)s.x;   // src < 2^17
        int p1 = atomicAdd(&cur[d.y >> 7], 1);
        ebuf[p1] = ((unsigned)(d.y & 127) << 17) | (unsigned)s.y;
        int p2 = atomicAdd(&cur[d.z >> 7], 1);
        ebuf[p2] = ((unsigned)(d.z & 127) << 17) | (unsigned)s.z;
        int p3 = atomicAdd(&cur[d.w >> 7], 1);
        ebuf[p3] = ((unsigned)(d.w & 127) << 17) | (unsigned)s.w;
    }
}

// bscan: exclusive scan of (bucket edge count + 128 self-loops) -> bucket rowptr base

__global__ void bscan_kernel(const int* __restrict__ gcur, int* __restrict__ bR0) {
    __shared__ int tmp[1024];
    int t = threadIdx.x;
    int v = (t < NBUCK) ? (gcur[t] - t * CAP + 128) : 0;
    tmp[t] = v;
    __syncthreads();
    for (int off = 1; off < 1024; off <<= 1) {
        int y = (t >= off) ? tmp[t - off] : 0;
        __syncthreads();
        tmp[t] += y;
        __syncthreads();
    }
    if (t < NBUCK) bR0[t] = tmp[t] - v;   // exclusive prefix
}

// rankfill: per-bucket rank; cnt scan -> rowptr/dinv/self-loop; csr fill
// also emits xd[n] = float4(dinv[n] * x[n], pad) for the 3-dim layer-1 gather

__global__ __launch_bounds__(256)
void rankfill_kernel(const unsigned* __restrict__ ebuf, const int* __restrict__ gcur,
                     const int* __restrict__ bR0, u64* __restrict__ obuf,
                     int* __restrict__ rowptr, int* __restrict__ csr,
                     float* __restrict__ dinv,
                     const float* __restrict__ x, float4* __restrict__ xd) {
    __shared__ int cnt[128];
    __shared__ int rpl[128];
    __shared__ int wsum[2];
    __shared__ int ocnt;
    __shared__ unsigned stash[STASH];
    const int tid = threadIdx.x, b = blockIdx.x;
    if (tid < 128) cnt[tid] = 0;
    if (tid == 0) ocnt = 0;
    __syncthreads();
    const int E0 = b * CAP;
    const int RL = gcur[b] - E0;          // bucket edge count (<= CAP = STASH)
    const int R0 = bR0[b];                // global rowptr base for this bucket
    for (int off = tid; off < RL; off += 256) {
        unsigned v = ebuf[E0 + off];
        int key = (v >> 17) & 0x7F;
        int r = atomicAdd(&cnt[key], 1);
        if (r < 128) {
            stash[off] = ((unsigned)r << 24) | v;
        } else {                                      // ~ never (deg >= 128)
            stash[off] = 0xFFFFFFFFu;
            int oi = atomicAdd(&ocnt, 1);
            obuf[(size_t)b * OBSTRIDE + oi] =
                ((u64)r << 40) | ((u64)key << 32) | (u64)(v & 0x1FFFFu);
        }
    }
    __syncthreads();
    const int lane = tid & 63, w = tid >> 6;
    int xcnt = (tid < 128) ? cnt[tid] : 0;
    int inc = xcnt;
#pragma unroll
    for (int off = 1; off < 64; off <<= 1) {
        int y = __shfl_up(inc, off, 64);
        if (lane >= off) inc += y;
    }
    if (lane == 63 && w < 2) wsum[w] = inc;
    __syncthreads();
    if (tid < 128) {
        int base = (w == 1) ? wsum[0] : 0;
        int pre = base + inc - xcnt;
        const int n = b * 128 + tid;
        const int rpn = R0 + tid + pre;   // bucket base + in-bucket self-loops + edge prefix
        rpl[tid] = rpn;
        if (n < N_NODES) {
            rowptr[n] = rpn;
            float di = rsqrtf((float)(xcnt + 1));
            dinv[n] = di;
            csr[rpn + xcnt] = n;          // self-loop at end of node's list
            xd[n] = make_float4(x[n * 3 + 0] * di, x[n * 3 + 1] * di, x[n * 3 + 2] * di, 0.f);
        }
    }
    if (b == NBUCK - 1 && tid == 0) rowptr[N_NODES] = EP;
    __syncthreads();
    for (int off = tid; off < RL; off += 256) {
        unsigned v = stash[off];
        if (v == 0xFFFFFFFFu) continue;
        csr[rpl[(v >> 17) & 0x7F] + (v >> 24)] = (int)(v & 0x1FFFFu);
    }
    for (int j = tid; j < ocnt; j += 256) {             // ~ never
        u64 pk = obuf[(size_t)b * OBSTRIDE + j];
        csr[rpl[(pk >> 32) & 0xFF] + (int)(pk >> 40)] = (int)(pk & 0x1FFFFu);
    }
}

// ================= fused layer (R17-proven): block = 16-node tile =================

__device__ __forceinline__ void addp(float4& a, uint2 u, bool pred) {
    __half2 h0 = *(__half2*)&u.x, h1 = *(__half2*)&u.y;
    float2 x = __half22float2(h0), y = __half22float2(h1);
    if (pred) { a.x += x.x; a.y += x.y; a.z += y.x; a.w += y.y; }
}

__device__ __forceinline__ void bfly_store_lds(float4 acc, const float4 b4, float di,
                                               int g, int p, int l, _Float16* __restrict__ tl) {
    acc.x += __shfl_xor(acc.x, 16, 64);
    acc.y += __shfl_xor(acc.y, 16, 64);
    acc.z += __shfl_xor(acc.z, 16, 64);
    acc.w += __shfl_xor(acc.w, 16, 64);
    acc.x += __shfl_xor(acc.x, 32, 64);
    acc.y += __shfl_xor(acc.y, 32, 64);
    acc.z += __shfl_xor(acc.z, 32, 64);
    acc.w += __shfl_xor(acc.w, 32, 64);
    if (g == 0) {
        half4_t hv;
        hv[0] = (_Float16)fmaxf(fmaf(di, acc.x, b4.x), 0.f);
        hv[1] = (_Float16)fmaxf(fmaf(di, acc.y, b4.y), 0.f);
        hv[2] = (_Float16)fmaxf(fmaf(di, acc.z, b4.z), 0.f);
        hv[3] = (_Float16)fmaxf(fmaf(di, acc.w, b4.w), 0.f);
        *(half4_t*)(tl + l * 72 + p * 4) = hv;
    }
}

__device__ __forceinline__ void gather_phase(const __half* __restrict__ gf,
                                             const int* __restrict__ rowptr,
                                             const int* __restrict__ csr,
                                             const float* __restrict__ dinv,
                                             const float* __restrict__ bias,
                                             int n0, int lane, int wid,
                                             _Float16* __restrict__ tl) {
    const int g = lane >> 4, p = lane & 15;
    const int nw = n0 + wid * NPN;
    int rp = rowptr[nw + min(lane, NPN)];
    const uint2* gf2 = (const uint2*)gf;
    const float4 b4 = ((const float4*)bias)[p];
    int begv[NPN], cntv[NPN], idxv[NPN];
    int end_prev = __shfl(rp, 0, 64);
#pragma unroll
    for (int i = 0; i < NPN; ++i) {
        int end = __shfl(rp, i + 1, 64);
        begv[i] = end_prev;
        cntv[i] = end - end_prev;
        end_prev = end;
        // predicated: masked lanes skip -> fewer 64B segments fetched
        idxv[i] = (lane < cntv[i]) ? csr[begv[i] + lane] : 0;
    }
#pragma unroll
    for (int ii = 0; ii < NPN; ii += 2) {
        const int la = wid * NPN + ii, lb = la + 1;
        const int ca = cntv[ii], cb = cntv[ii + 1];
        const int ba = begv[ii], bb = begv[ii + 1];
        const int iva = idxv[ii], ivb = idxv[ii + 1];
        int sa0 = __shfl(iva, g, 64),      sb0 = __shfl(ivb, g, 64);
        int sa1 = __shfl(iva, g + 4, 64),  sb1 = __shfl(ivb, g + 4, 64);
        int sa2 = __shfl(iva, g + 8, 64),  sb2 = __shfl(ivb, g + 8, 64);
        int sa3 = __shfl(iva, g + 12, 64), sb3 = __shfl(ivb, g + 12, 64);
        uint2 ua0 = gf2[(size_t)sa0 * 16 + p], ub0 = gf2[(size_t)sb0 * 16 + p];
        uint2 ua1 = gf2[(size_t)sa1 * 16 + p], ub1 = gf2[(size_t)sb1 * 16 + p];
        uint2 ua2 = gf2[(size_t)sa2 * 16 + p], ub2 = gf2[(size_t)sb2 * 16 + p];
        uint2 ua3 = gf2[(size_t)sa3 * 16 + p], ub3 = gf2[(size_t)sb3 * 16 + p];
        float4 accA = make_float4(0.f, 0.f, 0.f, 0.f);
        float4 accB = make_float4(0.f, 0.f, 0.f, 0.f);
        addp(accA, ua0, g + 0 < ca);  addp(accB, ub0, g + 0 < cb);
        addp(accA, ua1, g + 4 < ca);  addp(accB, ub1, g + 4 < cb);
        addp(accA, ua2, g + 8 < ca);  addp(accB, ub2, g + 8 < cb);
        addp(accA, ua3, g + 12 < ca); addp(accB, ub3, g + 12 < cb);
        if (ca > 16) {
#pragma unroll
            for (int k = 4; k < 8; ++k) {
                int e = g + 4 * k;
                int s = __shfl(iva, e, 64);
                addp(accA, gf2[(size_t)s * 16 + p], e < ca);
            }
            if (ca > 32) {
                for (int e = 32 + g; e < ca; e += 4) {
                    int s = (e < 64) ? __shfl(iva, e, 64) : csr[ba + e];
                    addp(accA, gf2[(size_t)s * 16 + p], true);
                }
            }
        }
        if (cb > 16) {
#pragma unroll
            for (int k = 4; k < 8; ++k) {
                int e = g + 4 * k;
                int s = __shfl(ivb, e, 64);
                addp(accB, gf2[(size_t)s * 16 + p], e < cb);
            }
            if (cb > 32) {
                for (int e = 32 + g; e < cb; e += 4) {
                    int s = (e < 64) ? __shfl(ivb, e, 64) : csr[bb + e];
                    addp(accB, gf2[(size_t)s * 16 + p], true);
                }
            }
        }
        bfly_store_lds(accA, b4, dinv[n0 + la], g, p, la, tl);
        bfly_store_lds(accB, b4, dinv[n0 + lb], g, p, lb, tl);
    }
}

// ================= fused layer 1: 3-dim fp32 gather (linearity: agg before @W1) =================
// out[d] = dinv[d] * (Σ_{s∈N(d)∪{d}} dinv[s]*x[s]) @ W1 + b1 ; relu ; then @W2 MFMA tail.
// xd (1.6 MB float4) is L2-resident on every XCD -> 16 B/edge instead of 128 B/edge.

__global__ __launch_bounds__(256, 8)
void fused_layer1_kernel(const float4* __restrict__ xd, const int* __restrict__ rowptr,
                         const int* __restrict__ csr, const float* __restrict__ dinv,
                         const float* __restrict__ b1, const float* __restrict__ W1,
                         const float* __restrict__ W2, __half* __restrict__ gf_out) {
    __shared__ __align__(16) _Float16 tile[16 * 72];
    __shared__ __align__(16) _Float16 tile2[16 * 72];
    const int tid = threadIdx.x;
    const int lane = tid & 63, wid = tid >> 6;
    const int n0 = blockIdx.x * 16;

    // ---- 3-dim gather: node j = lane>>4 within wave, 16 lanes per node ----
    const int j = lane >> 4, p = lane & 15;
    const int l = wid * 4 + j;            // tile-local node 0..15
    const int node = n0 + l;
    const int beg = rowptr[node], end = rowptr[node + 1];
    float a0 = 0.f, a1 = 0.f, a2 = 0.f;
    for (int e = beg + p; e < end; e += 16) {
        float4 v = xd[csr[e]];
        a0 += v.x; a1 += v.y; a2 += v.z;
    }
#pragma unroll
    for (int off = 1; off < 16; off <<= 1) {
        a0 += __shfl_xor(a0, off, 64);
        a1 += __shfl_xor(a1, off, 64);
        a2 += __shfl_xor(a2, off, 64);
    }
    const float dd = dinv[node];
    const float4 w0 = ((const float4*)W1)[p];
    const float4 w1 = ((const float4*)(W1 + HID))[p];
    const float4 w2 = ((const float4*)(W1 + 2 * HID))[p];
    const float4 bb = ((const float4*)b1)[p];
    half4_t hv;
    hv[0] = (_Float16)fmaxf(fmaf(dd, a0 * w0.x + a1 * w1.x + a2 * w2.x, bb.x), 0.f);
    hv[1] = (_Float16)fmaxf(fmaf(dd, a0 * w0.y + a1 * w1.y + a2 * w2.y, bb.y), 0.f);
    hv[2] = (_Float16)fmaxf(fmaf(dd, a0 * w0.z + a1 * w1.z + a2 * w2.z, bb.z), 0.f);
    hv[3] = (_Float16)fmaxf(fmaf(dd, a0 * w0.w + a1 * w1.w + a2 * w2.w, bb.w), 0.f);
    *(half4_t*)(tile + l * 72 + p * 4) = hv;
    __syncthreads();

    // ---- MFMA tail: gf_out = dinv ⊙ (h1 @ W2), identical to fused_layer ----
    const int kg = lane >> 4, n = lane & 15;
    half8_t B0, B1;
#pragma unroll
    for (int jj = 0; jj < 8; ++jj) {
        B0[jj] = (_Float16)W2[(kg * 8 + jj) * HID + wid * 16 + n];
        B1[jj] = (_Float16)W2[(32 + kg * 8 + jj) * HID + wid * 16 + n];
    }
    half8_t A0 = *(const half8_t*)(tile + n * 72 + kg * 8);
    half8_t A1 = *(const half8_t*)(tile + n * 72 + 32 + kg * 8);
    f32x4_t c = {0.f, 0.f, 0.f, 0.f};
    c = __builtin_amdgcn_mfma_f32_16x16x32_f16(A0, B0, c, 0, 0, 0);
    c = __builtin_amdgcn_mfma_f32_16x16x32_f16(A1, B1, c, 0, 0, 0);

    const int q = lane >> 4;
#pragma unroll
    for (int r = 0; r < 4; ++r)
        tile2[(q * 4 + r) * 72 + wid * 16 + n] = (_Float16)(c[r] * dinv[n0 + q * 4 + r]);
    __syncthreads();
    const int row = tid >> 4, seg = tid & 15;
    uint2 v = *(const uint2*)(tile2 + row * 72 + seg * 4);
    *(uint2*)((__half*)gf_out + (size_t)(n0 + row) * HID + seg * 4) = v;
}

__global__ __launch_bounds__(256, 8)
void fused_layer_kernel(const __half* __restrict__ gf_in, const int* __restrict__ rowptr,
                        const int* __restrict__ csr, const float* __restrict__ dinv,
                        const float* __restrict__ bias, const float* __restrict__ W,
                        __half* __restrict__ gf_out) {
    __shared__ __align__(16) _Float16 tile[16 * 72];
    __shared__ __align__(16) _Float16 tile2[16 * 72];
    const int tid = threadIdx.x;
    const int lane = tid & 63, wid = tid >> 6;
    const int n0 = blockIdx.x * 16;

    gather_phase(gf_in, rowptr, csr, dinv, bias, n0, lane, wid, tile);
    __syncthreads();

    const int kg = lane >> 4, n = lane & 15;
    half8_t B0, B1;
#pragma unroll
    for (int j = 0; j < 8; ++j) {
        B0[j] = (_Float16)W[(kg * 8 + j) * HID + wid * 16 + n];
        B1[j] = (_Float16)W[(32 + kg * 8 + j) * HID + wid * 16 + n];
    }
    half8_t A0 = *(const half8_t*)(tile + n * 72 + kg * 8);
    half8_t A1 = *(const half8_t*)(tile + n * 72 + 32 + kg * 8);
    f32x4_t c = {0.f, 0.f, 0.f, 0.f};
    c = __builtin_amdgcn_mfma_f32_16x16x32_f16(A0, B0, c, 0, 0, 0);
    c = __builtin_amdgcn_mfma_f32_16x16x32_f16(A1, B1, c, 0, 0, 0);

    const int q = lane >> 4;
#pragma unroll
    for (int r = 0; r < 4; ++r)
        tile2[(q * 4 + r) * 72 + wid * 16 + n] = (_Float16)(c[r] * dinv[n0 + q * 4 + r]);
    __syncthreads();
    const int row = tid >> 4, seg = tid & 15;
    uint2 v = *(const uint2*)(tile2 + row * 72 + seg * 4);
    *(uint2*)((__half*)gf_out + (size_t)(n0 + row) * HID + seg * 4) = v;
}

// ================= fused final: gather -> hv LDS -> MFMA(Wm1) + head + sigmoid =================

__global__ __launch_bounds__(256, 8)
void fused_final_kernel(const __half* __restrict__ gf_in, const int* __restrict__ rowptr,
                        const int* __restrict__ csr, const float* __restrict__ dinv,
                        const float* __restrict__ b3, const float* __restrict__ Wm1,
                        const float* __restrict__ bm1, const float* __restrict__ Wm2,
                        const float* __restrict__ bm2, float* __restrict__ out) {
    __shared__ __align__(16) _Float16 tile[16 * 72];
    __shared__ float redbuf[4][16];
    const int tid = threadIdx.x;
    const int lane = tid & 63, wid = tid >> 6;
    const int n0 = blockIdx.x * 16;

    gather_phase(gf_in, rowptr, csr, dinv, b3, n0, lane, wid, tile);
    __syncthreads();

    const int kg = lane >> 4, n = lane & 15;
    half8_t B0, B1;
#pragma unroll
    for (int j = 0; j < 8; ++j) {
        B0[j] = (_Float16)Wm1[(kg * 8 + j) * HID + wid * 16 + n];
        B1[j] = (_Float16)Wm1[(32 + kg * 8 + j) * HID + wid * 16 + n];
    }
    half8_t A0 = *(const half8_t*)(tile + n * 72 + kg * 8);
    half8_t A1 = *(const half8_t*)(tile + n * 72 + 32 + kg * 8);
    f32x4_t c = {0.f, 0.f, 0.f, 0.f};
    c = __builtin_amdgcn_mfma_f32_16x16x32_f16(A0, B0, c, 0, 0, 0);
    c = __builtin_amdgcn_mfma_f32_16x16x32_f16(A1, B1, c, 0, 0, 0);

    const float bm1c = bm1[wid * 16 + n];
    const float wm2c = Wm2[wid * 16 + n];
    float part[4];
#pragma unroll
    for (int r = 0; r < 4; ++r) part[r] = fmaxf(c[r] + bm1c, 0.0f) * wm2c;
#pragma unroll
    for (int off = 1; off < 16; off <<= 1)
#pragma unroll
        for (int r = 0; r < 4; ++r) part[r] += __shfl_xor(part[r], off, 64);
    const int q = lane >> 4;
    if (n == 0) {
#pragma unroll
        for (int r = 0; r < 4; ++r) redbuf[wid][q * 4 + r] = part[r];
    }
    __syncthreads();
    if (tid < 16) {
        float s = redbuf[0][tid] + redbuf[1][tid] + redbuf[2][tid] + redbuf[3][tid];
        out[n0 + tid] = 1.0f / (1.0f + expf(-(s + bm2[0])));
    }
}

// ---------------- launch ----------------

extern "C" void kernel_launch(void* const* d_in, const int* in_sizes, int n_in,
                              void* d_out, int out_size, void* d_ws, size_t ws_size,
                              hipStream_t stream) {
    const float* x   = (const float*)d_in[0];
    const int*   ei  = (const int*)d_in[1];
    const float* W1  = (const float*)d_in[2];
    const float* b1  = (const float*)d_in[3];
    const float* W2  = (const float*)d_in[4];
    const float* b2  = (const float*)d_in[5];
    const float* W3  = (const float*)d_in[6];
    const float* b3  = (const float*)d_in[7];
    const float* Wm1 = (const float*)d_in[8];
    const float* bm1 = (const float*)d_in[9];
    const float* Wm2 = (const float*)d_in[10];
    const float* bm2 = (const float*)d_in[11];
    float* out = (float*)d_out;

    const int* src = ei;
    const int* dst = ei + N_EDGES;

    char* ws = (char*)d_ws;
    size_t off = 0;
    auto alloc = [&](size_t bytes) { size_t o = off; off = (off + bytes + 255) & ~(size_t)255; return (void*)(ws + o); };
    int*      rowptr = (int*)alloc(4ll * (N_NODES + 1));
    int*      gcur   = (int*)alloc(4ll * NBUCK);
    int*      bR0    = (int*)alloc(4ll * NBUCK);
    int*      csr    = (int*)alloc(4ll * (EP + 64));       // +64 pad (zeros)
    float*    dinv   = (float*)alloc(4ll * N_NODES);
    float4*   xd     = (float4*)alloc(16ll * N_NODES);     // dinv*x packed, 1.6 MB (L2-resident)
    __half*   gfA    = (__half*)alloc(2ll * N_NODES * HID);
    __half*   gfB    = (__half*)alloc(2ll * N_NODES * HID);
    unsigned* ebuf   = (unsigned*)alloc(4ll * (size_t)NBUCK * CAP);
    u64*      obuf   = (u64*)alloc(8ll * (size_t)NBUCK * OBSTRIDE);
    (void)ws_size;

    // --- CSR build v7: 4 dispatches, 128-node buckets, full-chip grids ---
    init_kernel<<<1, 512, 0, stream>>>(gcur, csr);
    scatter_kernel<<<NCHUNK, 1024, 0, stream>>>(src, dst, gcur, ebuf);
    bscan_kernel<<<1, 1024, 0, stream>>>(gcur, bR0);
    rankfill_kernel<<<NBUCK, 256, 0, stream>>>(ebuf, gcur, bR0, obuf, rowptr, csr, dinv, x, xd);

    // --- layers: layer1 folded into fused_layer1 via linearity (3-dim fp32 gather) ---
    fused_layer1_kernel<<<NTILE, 256, 0, stream>>>(xd, rowptr, csr, dinv, b1, W1, W2, gfB);
    fused_layer_kernel<<<NTILE, 256, 0, stream>>>(gfB, rowptr, csr, dinv, b2, W3, gfA);
    fused_final_kernel<<<NTILE, 256, 0, stream>>>(gfA, rowptr, csr, dinv, b3, Wm1, bm1, Wm2, bm2, out);
}